// Round 4
// baseline (450.579 us; speedup 1.0000x reference)
//
#include <hip/hip_runtime.h>
#include <hip/hip_bf16.h>

#define NN 50000
#define NE 800000
#define DD 256
#define KK 512   // concat K for fused GEMM
#define SCAN_NB 49  // ceil(NN/1024)

typedef unsigned short u16;
typedef unsigned int   u32;
typedef __attribute__((ext_vector_type(8))) __bf16 bf16x8;
typedef __attribute__((ext_vector_type(4))) float  f32x4;
typedef __attribute__((ext_vector_type(8))) u16    u16x8;
typedef __attribute__((ext_vector_type(4))) u16    u16x4;

static __device__ __forceinline__ u16 f2bf(float f) {
  u32 u = __float_as_uint(f);
  u32 r = (u + 0x7FFFu + ((u >> 16) & 1u)) >> 16;
  return (u16)r;
}
static __device__ __forceinline__ float bf2f(u16 h) {
  return __uint_as_float(((u32)h) << 16);
}

// ---------------- CSR build ----------------
__global__ void k_histo(const int* __restrict__ tgt, int* __restrict__ deg) {
  int i = blockIdx.x * 256 + threadIdx.x;
  if (i < NE) atomicAdd(&deg[tgt[i]], 1);
}

// two-level scan: phase 1 — per-block (1024 elems) exclusive scan + block sum
__global__ void k_scan1(const int* __restrict__ deg, int* __restrict__ locx,
                        int* __restrict__ bsum) {
  __shared__ int wsum[16];
  const int i = blockIdx.x * 1024 + threadIdx.x;
  const int lane = threadIdx.x & 63, wid = threadIdx.x >> 6;
  int v = (i < NN) ? deg[i] : 0;
  int s = v;
#pragma unroll
  for (int d = 1; d < 64; d <<= 1) {
    int t = __shfl_up(s, d, 64);
    if (lane >= d) s += t;
  }
  if (lane == 63) wsum[wid] = s;
  __syncthreads();
  if (wid == 0) {
    int ws = (lane < 16) ? wsum[lane] : 0;
#pragma unroll
    for (int d = 1; d < 16; d <<= 1) {
      int t = __shfl_up(ws, d, 64);
      if (lane >= d) ws += t;
    }
    if (lane < 16) wsum[lane] = ws;
    if (lane == 15) bsum[blockIdx.x] = ws;
  }
  __syncthreads();
  int excl = s - v + (wid ? wsum[wid - 1] : 0);
  if (i < NN) locx[i] = excl;
}

// phase 2 — 1-wave exclusive scan of 49 block sums
__global__ void k_scan2(const int* __restrict__ bsum, int* __restrict__ boff) {
  const int lane = threadIdx.x;
  int v = (lane < SCAN_NB) ? bsum[lane] : 0;
  int s = v;
#pragma unroll
  for (int d = 1; d < 64; d <<= 1) {
    int t = __shfl_up(s, d, 64);
    if (lane >= d) s += t;
  }
  if (lane < SCAN_NB) boff[lane] = s - v;
}

// phase 3 — add block offsets, write off + cursor
__global__ void k_scan3(const int* __restrict__ locx, const int* __restrict__ boff,
                        int* __restrict__ off, int* __restrict__ cursor) {
  const int i = blockIdx.x * 1024 + threadIdx.x;
  if (i < NN) {
    int o = locx[i] + boff[blockIdx.x];
    off[i] = o;
    cursor[i] = o;
  }
  if (i == 0) off[NN] = NE;
}

__global__ void k_fill(const int* __restrict__ src, const int* __restrict__ tgt,
                       int* __restrict__ cursor, int* __restrict__ col) {
  int i = blockIdx.x * 256 + threadIdx.x;
  if (i < NE) {
    int p = atomicAdd(&cursor[tgt[i]], 1);
    col[p] = src[i];
  }
}

// ---------------- dtype prep ----------------
__global__ void k_f32_to_bf16(const float* __restrict__ in, u16* __restrict__ out, int n4) {
  int i = blockIdx.x * 256 + threadIdx.x;
  if (i >= n4) return;
  const float4 v = *reinterpret_cast<const float4*>(in + i * 4);
  u16x4 o; o.x = f2bf(v.x); o.y = f2bf(v.y); o.z = f2bf(v.z); o.w = f2bf(v.w);
  *reinterpret_cast<u16x4*>(out + i * 4) = o;
}

// WcT[n][k] (bf16, [256][512]) for BOTH layers in one launch
__global__ void k_make_wcT(const float* __restrict__ W1l, const float* __restrict__ W1r,
                           const float* __restrict__ W2l, const float* __restrict__ W2r,
                           u16* __restrict__ Wc1T, u16* __restrict__ Wc2T) {
  int gid = blockIdx.x * 256 + threadIdx.x;  // 262144 total
  int layer = gid >> 17;
  int idx = gid & 131071;
  int n = idx >> 9, k = idx & 511;
  const float* Wl = layer ? W2l : W1l;
  const float* Wr = layer ? W2r : W1r;
  u16* WcT = layer ? Wc2T : Wc1T;
  float v = (k < DD) ? Wl[k * DD + n] : Wr[(k - DD) * DD + n];
  WcT[idx] = f2bf(v);
}

// ---------------- mean aggregation (CSR, XCD feature-sliced) ----------------
// blockIdx % 8 = feature slice (32 feats = 64 B) -> pinned to one XCD via
// round-robin dispatch; per-XCD gather working set = 50k x 64 B = 3.2 MB (L2-fit).
// Block = 4 waves, 1 node/wave. Wave: 8 edge-groups x 8 lanes x 8 B loads.
__global__ void k_aggregate(const u16* __restrict__ feat, const int* __restrict__ off,
                            const int* __restrict__ col, u16* __restrict__ out) {
  const int slice = blockIdx.x & 7;
  const int nb    = blockIdx.x >> 3;
  const int wave  = threadIdx.x >> 6;
  const int lane  = threadIdx.x & 63;
  const int node  = nb * 4 + wave;
  const int g  = lane >> 3;   // edge group 0..7
  const int gl = lane & 7;    // lane within group
  const int s = off[node], e = off[node + 1];
  const int fo = slice * 32 + gl * 4;  // u16 offset within row (64 B slice)
  float a0 = 0.f, a1 = 0.f, a2 = 0.f, a3 = 0.f;
  for (int i = s + g; i < e; i += 8) {
    int c = col[i];
    u16x4 v = *reinterpret_cast<const u16x4*>(feat + c * DD + fo);
    a0 += bf2f(v.x); a1 += bf2f(v.y); a2 += bf2f(v.z); a3 += bf2f(v.w);
  }
  // reduce across the 8 edge-groups (stride 8,16,32)
#pragma unroll
  for (int m = 8; m < 64; m <<= 1) {
    a0 += __shfl_xor(a0, m, 64);
    a1 += __shfl_xor(a1, m, 64);
    a2 += __shfl_xor(a2, m, 64);
    a3 += __shfl_xor(a3, m, 64);
  }
  if (g == 0) {
    const float scale = (e > s) ? 1.0f / (float)(e - s) : 0.0f;
    u16x4 o;
    o.x = f2bf(a0 * scale); o.y = f2bf(a1 * scale);
    o.z = f2bf(a2 * scale); o.w = f2bf(a3 * scale);
    *reinterpret_cast<u16x4*>(out + node * DD + fo) = o;
  }
}

// ---------------- fused GEMM: out = [A0|A1] @ Wc + bias (+relu) ----------------
#define BM 128
#define BN 128
#define BK 64

template <int LAYER>
__global__ void k_gemm_fused(const u16* __restrict__ A0, const u16* __restrict__ A1,
                             const u16* __restrict__ WcT, const float* __restrict__ bias,
                             u16* __restrict__ outb, float* __restrict__ outf, int M) {
  __shared__ alignas(16) u16 lA[BM * BK];
  __shared__ alignas(16) u16 lB[BN * BK];
  const int tid = threadIdx.x;
  const int rowBase = blockIdx.x * BM;
  const int colBase = blockIdx.y * BN;
  const int wave = tid >> 6, lane = tid & 63;
  const int wr = wave >> 1, wc = wave & 1;  // 2x2 waves, 64x64 each

  f32x4 acc[4][4] = {};

  const int sr = tid >> 3;          // 0..31 staging row within 32-row group
  const int sc = (tid & 7) * 8;     // bf16 col offset 0..56

  for (int k0 = 0; k0 < KK; k0 += BK) {
    if (k0) __syncthreads();
    const u16* Asrc = (k0 < DD) ? A0 : A1;
    const int kk = k0 & (DD - 1);
#pragma unroll
    for (int it = 0; it < 4; ++it) {
      int row = it * 32 + sr;
      int grow = rowBase + row;
      int gr = (grow < M) ? grow : 0;
      u16x8 v = *reinterpret_cast<const u16x8*>(Asrc + gr * DD + kk + sc);
      int kb = (sc * 2) ^ ((row & 7) << 4);
      *reinterpret_cast<u16x8*>((char*)lA + row * 128 + kb) = v;
    }
#pragma unroll
    for (int it = 0; it < 4; ++it) {
      int row = it * 32 + sr;  // n within tile
      u16x8 v = *reinterpret_cast<const u16x8*>(WcT + (colBase + row) * KK + k0 + sc);
      int kb = (sc * 2) ^ ((row & 7) << 4);
      *reinterpret_cast<u16x8*>((char*)lB + row * 128 + kb) = v;
    }
    __syncthreads();

#pragma unroll
    for (int ks = 0; ks < 2; ++ks) {
      const int kbyte = ks * 64 + (lane >> 4) * 16;
      bf16x8 af[4], bfg[4];
#pragma unroll
      for (int m = 0; m < 4; ++m) {
        int row = wr * 64 + m * 16 + (lane & 15);
        af[m] = *reinterpret_cast<const bf16x8*>((const char*)lA + row * 128 + (kbyte ^ ((row & 7) << 4)));
      }
#pragma unroll
      for (int n = 0; n < 4; ++n) {
        int row = wc * 64 + n * 16 + (lane & 15);
        bfg[n] = *reinterpret_cast<const bf16x8*>((const char*)lB + row * 128 + (kbyte ^ ((row & 7) << 4)));
      }
#pragma unroll
      for (int m = 0; m < 4; ++m)
#pragma unroll
        for (int n = 0; n < 4; ++n)
          acc[m][n] = __builtin_amdgcn_mfma_f32_16x16x32_bf16(af[m], bfg[n], acc[m][n], 0, 0, 0);
    }
  }

  // epilogue: D layout col = lane&15, row = (lane>>4)*4 + reg  [m89-verified]
  const int lrow = (lane >> 4) * 4;
  const int lcol = lane & 15;
#pragma unroll
  for (int n = 0; n < 4; ++n) {
    const int gcol = colBase + wc * 64 + n * 16 + lcol;
    const float bv = bias[gcol];
#pragma unroll
    for (int m = 0; m < 4; ++m) {
#pragma unroll
      for (int r = 0; r < 4; ++r) {
        const int grow = rowBase + wr * 64 + m * 16 + lrow + r;
        if (grow < M) {
          float v = acc[m][n][r] + bv;
          if (LAYER == 1) {
            v = fmaxf(v, 0.0f);
            outb[grow * DD + gcol] = f2bf(v);
          } else {
            outf[grow * DD + gcol] = v;
          }
        }
      }
    }
  }
}

// ---------------- launch ----------------
extern "C" void kernel_launch(void* const* d_in, const int* in_sizes, int n_in,
                              void* d_out, int out_size, void* d_ws, size_t ws_size,
                              hipStream_t stream) {
  const float* x    = (const float*)d_in[0];
  const int*   ei   = (const int*)d_in[1];
  const float* W1l  = (const float*)d_in[2];
  const float* b1   = (const float*)d_in[3];
  const float* W1r  = (const float*)d_in[4];
  const float* W2l  = (const float*)d_in[5];
  const float* b2   = (const float*)d_in[6];
  const float* W2r  = (const float*)d_in[7];
  float* out = (float*)d_out;

  const int* srcIdx = ei;        // edge_index[0]
  const int* tgtIdx = ei + NE;   // edge_index[1]

  char* ws = (char*)d_ws;
  int* deg    = (int*)(ws + 0);                       // 200000
  int* off    = (int*)(ws + 200064);                  // 200004
  int* cursor = (int*)(ws + 400128);                  // 200000
  int* col    = (int*)(ws + 600192);                  // 3200000
  u16* x_bf   = (u16*)(ws + 3800192);                 // 25600000
  u16* h_bf   = (u16*)(ws + 29400192);                // 25600000
  u16* agg_bf = (u16*)(ws + 55000192);                // 25600000
  u16* Wc1T   = (u16*)(ws + 80600192);                // 262144
  u16* Wc2T   = (u16*)(ws + 80862336);                // 262144
  int* locx   = (int*)(ws + 81124480);                // 200000
  int* bsum   = (int*)(ws + 81324480);                // 256
  int* boff   = (int*)(ws + 81324736);                // 256

  hipMemsetAsync(deg, 0, NN * sizeof(int), stream);
  k_histo<<<(NE + 255) / 256, 256, 0, stream>>>(tgtIdx, deg);
  k_scan1<<<SCAN_NB, 1024, 0, stream>>>(deg, locx, bsum);
  k_scan2<<<1, 64, 0, stream>>>(bsum, boff);
  k_scan3<<<SCAN_NB, 1024, 0, stream>>>(locx, boff, off, cursor);
  k_fill<<<(NE + 255) / 256, 256, 0, stream>>>(srcIdx, tgtIdx, cursor, col);

  k_f32_to_bf16<<<(NN * DD / 4 + 255) / 256, 256, 0, stream>>>(x, x_bf, NN * DD / 4);
  k_make_wcT<<<1024, 256, 0, stream>>>(W1l, W1r, W2l, W2r, Wc1T, Wc2T);

  dim3 ggrid((NN + BM - 1) / BM, DD / BN);
  const int agrid = (NN / 4) * 8;  // 12500 node-blocks x 8 slices

  // layer 1
  k_aggregate<<<agrid, 256, 0, stream>>>(x_bf, off, col, agg_bf);
  k_gemm_fused<1><<<ggrid, 256, 0, stream>>>(agg_bf, x_bf, Wc1T, b1, h_bf, nullptr, NN);
  // layer 2
  k_aggregate<<<agrid, 256, 0, stream>>>(h_bf, off, col, agg_bf);
  k_gemm_fused<2><<<ggrid, 256, 0, stream>>>(agg_bf, h_bf, Wc2T, b2, nullptr, out, NN);
}

// Round 5
// 290.138 us; speedup vs baseline: 1.5530x; 1.5530x over previous
//
#include <hip/hip_runtime.h>
#include <hip/hip_bf16.h>

#define NN 50000
#define NE 800000
#define DD 256
#define KK 512   // concat K for fused GEMM
#define SCAN_NB 49  // ceil(NN/1024)

typedef unsigned short u16;
typedef unsigned int   u32;
typedef __attribute__((ext_vector_type(8))) __bf16 bf16x8;
typedef __attribute__((ext_vector_type(4))) float  f32x4;
typedef __attribute__((ext_vector_type(8))) u16    u16x8;
typedef __attribute__((ext_vector_type(4))) u16    u16x4;

static __device__ __forceinline__ u16 f2bf(float f) {
  u32 u = __float_as_uint(f);
  u32 r = (u + 0x7FFFu + ((u >> 16) & 1u)) >> 16;
  return (u16)r;
}
static __device__ __forceinline__ float bf2f(u16 h) {
  return __uint_as_float(((u32)h) << 16);
}

// ---------------- CSR build ----------------
__global__ void k_histo(const int* __restrict__ tgt, int* __restrict__ deg) {
  int i = blockIdx.x * 256 + threadIdx.x;
  if (i < NE) atomicAdd(&deg[tgt[i]], 1);
}

// two-level scan: phase 1 — per-block (1024 elems) exclusive scan + block sum
__global__ void k_scan1(const int* __restrict__ deg, int* __restrict__ locx,
                        int* __restrict__ bsum) {
  __shared__ int wsum[16];
  const int i = blockIdx.x * 1024 + threadIdx.x;
  const int lane = threadIdx.x & 63, wid = threadIdx.x >> 6;
  int v = (i < NN) ? deg[i] : 0;
  int s = v;
#pragma unroll
  for (int d = 1; d < 64; d <<= 1) {
    int t = __shfl_up(s, d, 64);
    if (lane >= d) s += t;
  }
  if (lane == 63) wsum[wid] = s;
  __syncthreads();
  if (wid == 0) {
    int ws = (lane < 16) ? wsum[lane] : 0;
#pragma unroll
    for (int d = 1; d < 16; d <<= 1) {
      int t = __shfl_up(ws, d, 64);
      if (lane >= d) ws += t;
    }
    if (lane < 16) wsum[lane] = ws;
    if (lane == 15) bsum[blockIdx.x] = ws;
  }
  __syncthreads();
  int excl = s - v + (wid ? wsum[wid - 1] : 0);
  if (i < NN) locx[i] = excl;
}

// phase 2 — 1-wave exclusive scan of 49 block sums
__global__ void k_scan2(const int* __restrict__ bsum, int* __restrict__ boff) {
  const int lane = threadIdx.x;
  int v = (lane < SCAN_NB) ? bsum[lane] : 0;
  int s = v;
#pragma unroll
  for (int d = 1; d < 64; d <<= 1) {
    int t = __shfl_up(s, d, 64);
    if (lane >= d) s += t;
  }
  if (lane < SCAN_NB) boff[lane] = s - v;
}

// phase 3 — add block offsets, write off + cursor
__global__ void k_scan3(const int* __restrict__ locx, const int* __restrict__ boff,
                        int* __restrict__ off, int* __restrict__ cursor) {
  const int i = blockIdx.x * 1024 + threadIdx.x;
  if (i < NN) {
    int o = locx[i] + boff[blockIdx.x];
    off[i] = o;
    cursor[i] = o;
  }
  if (i == 0) off[NN] = NE;
}

__global__ void k_fill(const int* __restrict__ src, const int* __restrict__ tgt,
                       int* __restrict__ cursor, int* __restrict__ col) {
  int i = blockIdx.x * 256 + threadIdx.x;
  if (i < NE) {
    int p = atomicAdd(&cursor[tgt[i]], 1);
    col[p] = src[i];
  }
}

// ---------------- dtype prep ----------------
__global__ void k_f32_to_bf16(const float* __restrict__ in, u16* __restrict__ out, int n4) {
  int i = blockIdx.x * 256 + threadIdx.x;
  if (i >= n4) return;
  const float4 v = *reinterpret_cast<const float4*>(in + i * 4);
  u16x4 o; o.x = f2bf(v.x); o.y = f2bf(v.y); o.z = f2bf(v.z); o.w = f2bf(v.w);
  *reinterpret_cast<u16x4*>(out + i * 4) = o;
}

// WcT[n][k] (bf16, [256][512]) for BOTH layers in one launch
__global__ void k_make_wcT(const float* __restrict__ W1l, const float* __restrict__ W1r,
                           const float* __restrict__ W2l, const float* __restrict__ W2r,
                           u16* __restrict__ Wc1T, u16* __restrict__ Wc2T) {
  int gid = blockIdx.x * 256 + threadIdx.x;  // 262144 total
  int layer = gid >> 17;
  int idx = gid & 131071;
  int n = idx >> 9, k = idx & 511;
  const float* Wl = layer ? W2l : W1l;
  const float* Wr = layer ? W2r : W1r;
  u16* WcT = layer ? Wc2T : Wc1T;
  float v = (k < DD) ? Wl[k * DD + n] : Wr[(k - DD) * DD + n];
  WcT[idx] = f2bf(v);
}

// ---------------- mean aggregation (CSR) ----------------
// one wave per node; half-wave (32 lanes) per edge, 16 B (8 feats)/lane.
// 4 edges in flight per half-wave per iteration (MLP=4).
__global__ void k_aggregate(const u16* __restrict__ feat, const int* __restrict__ off,
                            const int* __restrict__ col, u16* __restrict__ out) {
  const int wave = threadIdx.x >> 6;
  const int lane = threadIdx.x & 63;
  const int half = lane >> 5;
  const int l32 = lane & 31;
  const int node = blockIdx.x * 4 + wave;
  const int s = off[node], e = off[node + 1];
  const int fo = l32 * 8;  // 8 bf16 = 16 B per lane
  float a[8] = {0.f, 0.f, 0.f, 0.f, 0.f, 0.f, 0.f, 0.f};

  int i = s + half;
  // main loop: 4 edges per half-wave per iteration (8 edges/wave/iter)
  for (; i + 6 < e; i += 8) {
    int c0 = col[i], c1 = col[i + 2], c2 = col[i + 4], c3 = col[i + 6];
    u16x8 v0 = *reinterpret_cast<const u16x8*>(feat + c0 * DD + fo);
    u16x8 v1 = *reinterpret_cast<const u16x8*>(feat + c1 * DD + fo);
    u16x8 v2 = *reinterpret_cast<const u16x8*>(feat + c2 * DD + fo);
    u16x8 v3 = *reinterpret_cast<const u16x8*>(feat + c3 * DD + fo);
#pragma unroll
    for (int j = 0; j < 8; ++j) a[j] += bf2f(v0[j]);
#pragma unroll
    for (int j = 0; j < 8; ++j) a[j] += bf2f(v1[j]);
#pragma unroll
    for (int j = 0; j < 8; ++j) a[j] += bf2f(v2[j]);
#pragma unroll
    for (int j = 0; j < 8; ++j) a[j] += bf2f(v3[j]);
  }
  // tail: 1 edge per half-wave per iteration
  for (; i < e; i += 2) {
    int c = col[i];
    u16x8 v = *reinterpret_cast<const u16x8*>(feat + c * DD + fo);
#pragma unroll
    for (int j = 0; j < 8; ++j) a[j] += bf2f(v[j]);
  }
  // combine halves: lane l += lane l^32
#pragma unroll
  for (int j = 0; j < 8; ++j) a[j] += __shfl_xor(a[j], 32, 64);

  if (half == 0) {
    const float scale = (e > s) ? 1.0f / (float)(e - s) : 0.0f;
    u16x8 o;
#pragma unroll
    for (int j = 0; j < 8; ++j) o[j] = f2bf(a[j] * scale);
    *reinterpret_cast<u16x8*>(out + node * DD + fo) = o;
  }
}

// ---------------- fused GEMM: out = [A0|A1] @ Wc + bias (+relu) ----------------
#define BM 128
#define BN 128
#define BK 64

template <int LAYER>
__global__ void k_gemm_fused(const u16* __restrict__ A0, const u16* __restrict__ A1,
                             const u16* __restrict__ WcT, const float* __restrict__ bias,
                             u16* __restrict__ outb, float* __restrict__ outf, int M) {
  __shared__ alignas(16) u16 lA[BM * BK];
  __shared__ alignas(16) u16 lB[BN * BK];
  const int tid = threadIdx.x;
  const int rowBase = blockIdx.x * BM;
  const int colBase = blockIdx.y * BN;
  const int wave = tid >> 6, lane = tid & 63;
  const int wr = wave >> 1, wc = wave & 1;  // 2x2 waves, 64x64 each

  f32x4 acc[4][4] = {};

  const int sr = tid >> 3;          // 0..31 staging row within 32-row group
  const int sc = (tid & 7) * 8;     // bf16 col offset 0..56

  for (int k0 = 0; k0 < KK; k0 += BK) {
    if (k0) __syncthreads();
    const u16* Asrc = (k0 < DD) ? A0 : A1;
    const int kk = k0 & (DD - 1);
#pragma unroll
    for (int it = 0; it < 4; ++it) {
      int row = it * 32 + sr;
      int grow = rowBase + row;
      int gr = (grow < M) ? grow : 0;
      u16x8 v = *reinterpret_cast<const u16x8*>(Asrc + gr * DD + kk + sc);
      int kb = (sc * 2) ^ ((row & 7) << 4);
      *reinterpret_cast<u16x8*>((char*)lA + row * 128 + kb) = v;
    }
#pragma unroll
    for (int it = 0; it < 4; ++it) {
      int row = it * 32 + sr;  // n within tile
      u16x8 v = *reinterpret_cast<const u16x8*>(WcT + (colBase + row) * KK + k0 + sc);
      int kb = (sc * 2) ^ ((row & 7) << 4);
      *reinterpret_cast<u16x8*>((char*)lB + row * 128 + kb) = v;
    }
    __syncthreads();

#pragma unroll
    for (int ks = 0; ks < 2; ++ks) {
      const int kbyte = ks * 64 + (lane >> 4) * 16;
      bf16x8 af[4], bfg[4];
#pragma unroll
      for (int m = 0; m < 4; ++m) {
        int row = wr * 64 + m * 16 + (lane & 15);
        af[m] = *reinterpret_cast<const bf16x8*>((const char*)lA + row * 128 + (kbyte ^ ((row & 7) << 4)));
      }
#pragma unroll
      for (int n = 0; n < 4; ++n) {
        int row = wc * 64 + n * 16 + (lane & 15);
        bfg[n] = *reinterpret_cast<const bf16x8*>((const char*)lB + row * 128 + (kbyte ^ ((row & 7) << 4)));
      }
#pragma unroll
      for (int m = 0; m < 4; ++m)
#pragma unroll
        for (int n = 0; n < 4; ++n)
          acc[m][n] = __builtin_amdgcn_mfma_f32_16x16x32_bf16(af[m], bfg[n], acc[m][n], 0, 0, 0);
    }
  }

  // epilogue: D layout col = lane&15, row = (lane>>4)*4 + reg  [m89-verified]
  const int lrow = (lane >> 4) * 4;
  const int lcol = lane & 15;
#pragma unroll
  for (int n = 0; n < 4; ++n) {
    const int gcol = colBase + wc * 64 + n * 16 + lcol;
    const float bv = bias[gcol];
#pragma unroll
    for (int m = 0; m < 4; ++m) {
#pragma unroll
      for (int r = 0; r < 4; ++r) {
        const int grow = rowBase + wr * 64 + m * 16 + lrow + r;
        if (grow < M) {
          float v = acc[m][n][r] + bv;
          if (LAYER == 1) {
            v = fmaxf(v, 0.0f);
            outb[grow * DD + gcol] = f2bf(v);
          } else {
            outf[grow * DD + gcol] = v;
          }
        }
      }
    }
  }
}

// ---------------- launch ----------------
extern "C" void kernel_launch(void* const* d_in, const int* in_sizes, int n_in,
                              void* d_out, int out_size, void* d_ws, size_t ws_size,
                              hipStream_t stream) {
  const float* x    = (const float*)d_in[0];
  const int*   ei   = (const int*)d_in[1];
  const float* W1l  = (const float*)d_in[2];
  const float* b1   = (const float*)d_in[3];
  const float* W1r  = (const float*)d_in[4];
  const float* W2l  = (const float*)d_in[5];
  const float* b2   = (const float*)d_in[6];
  const float* W2r  = (const float*)d_in[7];
  float* out = (float*)d_out;

  const int* srcIdx = ei;        // edge_index[0]
  const int* tgtIdx = ei + NE;   // edge_index[1]

  char* ws = (char*)d_ws;
  int* deg    = (int*)(ws + 0);                       // 200000
  int* off    = (int*)(ws + 200064);                  // 200004
  int* cursor = (int*)(ws + 400128);                  // 200000
  int* col    = (int*)(ws + 600192);                  // 3200000
  u16* x_bf   = (u16*)(ws + 3800192);                 // 25600000
  u16* h_bf   = (u16*)(ws + 29400192);                // 25600000
  u16* agg_bf = (u16*)(ws + 55000192);                // 25600000
  u16* Wc1T   = (u16*)(ws + 80600192);                // 262144
  u16* Wc2T   = (u16*)(ws + 80862336);                // 262144
  int* locx   = (int*)(ws + 81124480);                // 200000
  int* bsum   = (int*)(ws + 81324480);                // 256
  int* boff   = (int*)(ws + 81324736);                // 256

  hipMemsetAsync(deg, 0, NN * sizeof(int), stream);
  k_histo<<<(NE + 255) / 256, 256, 0, stream>>>(tgtIdx, deg);
  k_scan1<<<SCAN_NB, 1024, 0, stream>>>(deg, locx, bsum);
  k_scan2<<<1, 64, 0, stream>>>(bsum, boff);
  k_scan3<<<SCAN_NB, 1024, 0, stream>>>(locx, boff, off, cursor);
  k_fill<<<(NE + 255) / 256, 256, 0, stream>>>(srcIdx, tgtIdx, cursor, col);

  k_f32_to_bf16<<<(NN * DD / 4 + 255) / 256, 256, 0, stream>>>(x, x_bf, NN * DD / 4);
  k_make_wcT<<<1024, 256, 0, stream>>>(W1l, W1r, W2l, W2r, Wc1T, Wc2T);

  dim3 ggrid((NN + BM - 1) / BM, DD / BN);

  // layer 1
  k_aggregate<<<NN / 4, 256, 0, stream>>>(x_bf, off, col, agg_bf);
  k_gemm_fused<1><<<ggrid, 256, 0, stream>>>(agg_bf, x_bf, Wc1T, b1, h_bf, nullptr, NN);
  // layer 2
  k_aggregate<<<NN / 4, 256, 0, stream>>>(h_bf, off, col, agg_bf);
  k_gemm_fused<2><<<ggrid, 256, 0, stream>>>(agg_bf, h_bf, Wc2T, b2, nullptr, out, NN);
}

// Round 6
// 242.937 us; speedup vs baseline: 1.8547x; 1.1943x over previous
//
#include <hip/hip_runtime.h>
#include <hip/hip_bf16.h>

#define NN 50000
#define NE 800000
#define DD 256
#define KK 512    // concat K for fused GEMM
#define PAD 128   // padded CSR row stride (max deg ~45 at 8 sigma; unreachable)
#define CSTR 16   // cnt stride in ints (64 B -> one cacheline per counter)

typedef unsigned short u16;
typedef unsigned int   u32;
typedef __attribute__((ext_vector_type(8))) __bf16 bf16x8;
typedef __attribute__((ext_vector_type(4))) float  f32x4;
typedef __attribute__((ext_vector_type(8))) u16    u16x8;
typedef __attribute__((ext_vector_type(4))) u16    u16x4;

static __device__ __forceinline__ u16 f2bf(float f) {
  u32 u = __float_as_uint(f);
  u32 r = (u + 0x7FFFu + ((u >> 16) & 1u)) >> 16;
  return (u16)r;
}
static __device__ __forceinline__ float bf2f(u16 h) {
  return __uint_as_float(((u32)h) << 16);
}

// ---------------- padded-CSR build: histogram+fill in ONE kernel ----------------
// cnt[node*CSTR] both counts and serves as insertion cursor; col_pad[node*PAD+p].
__global__ void k_fill2(const int* __restrict__ src, const int* __restrict__ tgt,
                        int* __restrict__ cnt, int* __restrict__ col) {
  int i = blockIdx.x * 256 + threadIdx.x;
  if (i < NE) {
    int t = tgt[i];
    int p = atomicAdd(&cnt[t * CSTR], 1);
    if (p < PAD) col[t * PAD + p] = src[i];
  }
}

// ---------------- dtype prep ----------------
__global__ void k_f32_to_bf16(const float* __restrict__ in, u16* __restrict__ out, int n4) {
  int i = blockIdx.x * 256 + threadIdx.x;
  if (i >= n4) return;
  const float4 v = *reinterpret_cast<const float4*>(in + i * 4);
  u16x4 o; o.x = f2bf(v.x); o.y = f2bf(v.y); o.z = f2bf(v.z); o.w = f2bf(v.w);
  *reinterpret_cast<u16x4*>(out + i * 4) = o;
}

// WcT[n][k] (bf16, [256][512]) for BOTH layers in one launch
__global__ void k_make_wcT(const float* __restrict__ W1l, const float* __restrict__ W1r,
                           const float* __restrict__ W2l, const float* __restrict__ W2r,
                           u16* __restrict__ Wc1T, u16* __restrict__ Wc2T) {
  int gid = blockIdx.x * 256 + threadIdx.x;  // 262144 total
  int layer = gid >> 17;
  int idx = gid & 131071;
  int n = idx >> 9, k = idx & 511;
  const float* Wl = layer ? W2l : W1l;
  const float* Wr = layer ? W2r : W1r;
  u16* WcT = layer ? Wc2T : Wc1T;
  float v = (k < DD) ? Wl[k * DD + n] : Wr[(k - DD) * DD + n];
  WcT[idx] = f2bf(v);
}

// ---------------- mean aggregation (padded CSR) ----------------
// one wave per node; half-wave (32 lanes) per edge, 16 B (8 feats)/lane.
// 4 edges in flight per half-wave per iteration (MLP=4).
__global__ void k_aggregate(const u16* __restrict__ feat, const int* __restrict__ cnt,
                            const int* __restrict__ col, u16* __restrict__ out) {
  const int wave = threadIdx.x >> 6;
  const int lane = threadIdx.x & 63;
  const int half = lane >> 5;
  const int l32 = lane & 31;
  const int node = blockIdx.x * 4 + wave;
  int deg = cnt[node * CSTR];
  if (deg > PAD) deg = PAD;       // unreachable clamp, keeps mean consistent
  const int s = node * PAD, e = s + deg;
  const int fo = l32 * 8;  // 8 bf16 = 16 B per lane
  float a[8] = {0.f, 0.f, 0.f, 0.f, 0.f, 0.f, 0.f, 0.f};

  int i = s + half;
  // main loop: 4 edges per half-wave per iteration (8 edges/wave/iter)
  for (; i + 6 < e; i += 8) {
    int c0 = col[i], c1 = col[i + 2], c2 = col[i + 4], c3 = col[i + 6];
    u16x8 v0 = *reinterpret_cast<const u16x8*>(feat + c0 * DD + fo);
    u16x8 v1 = *reinterpret_cast<const u16x8*>(feat + c1 * DD + fo);
    u16x8 v2 = *reinterpret_cast<const u16x8*>(feat + c2 * DD + fo);
    u16x8 v3 = *reinterpret_cast<const u16x8*>(feat + c3 * DD + fo);
#pragma unroll
    for (int j = 0; j < 8; ++j) a[j] += bf2f(v0[j]);
#pragma unroll
    for (int j = 0; j < 8; ++j) a[j] += bf2f(v1[j]);
#pragma unroll
    for (int j = 0; j < 8; ++j) a[j] += bf2f(v2[j]);
#pragma unroll
    for (int j = 0; j < 8; ++j) a[j] += bf2f(v3[j]);
  }
  // tail: 1 edge per half-wave per iteration
  for (; i < e; i += 2) {
    int c = col[i];
    u16x8 v = *reinterpret_cast<const u16x8*>(feat + c * DD + fo);
#pragma unroll
    for (int j = 0; j < 8; ++j) a[j] += bf2f(v[j]);
  }
  // combine halves: lane l += lane l^32
#pragma unroll
  for (int j = 0; j < 8; ++j) a[j] += __shfl_xor(a[j], 32, 64);

  if (half == 0) {
    const float scale = (deg > 0) ? 1.0f / (float)deg : 0.0f;
    u16x8 o;
#pragma unroll
    for (int j = 0; j < 8; ++j) o[j] = f2bf(a[j] * scale);
    *reinterpret_cast<u16x8*>(out + node * DD + fo) = o;
  }
}

// ---------------- fused GEMM: out = [A0|A1] @ Wc + bias (+relu) ----------------
#define BM 128
#define BN 128
#define BK 64

template <int LAYER>
__global__ void k_gemm_fused(const u16* __restrict__ A0, const u16* __restrict__ A1,
                             const u16* __restrict__ WcT, const float* __restrict__ bias,
                             u16* __restrict__ outb, float* __restrict__ outf, int M) {
  __shared__ alignas(16) u16 lA[BM * BK];
  __shared__ alignas(16) u16 lB[BN * BK];
  const int tid = threadIdx.x;
  const int rowBase = blockIdx.x * BM;
  const int colBase = blockIdx.y * BN;
  const int wave = tid >> 6, lane = tid & 63;
  const int wr = wave >> 1, wc = wave & 1;  // 2x2 waves, 64x64 each

  f32x4 acc[4][4] = {};

  const int sr = tid >> 3;          // 0..31 staging row within 32-row group
  const int sc = (tid & 7) * 8;     // bf16 col offset 0..56

  for (int k0 = 0; k0 < KK; k0 += BK) {
    if (k0) __syncthreads();
    const u16* Asrc = (k0 < DD) ? A0 : A1;
    const int kk = k0 & (DD - 1);
#pragma unroll
    for (int it = 0; it < 4; ++it) {
      int row = it * 32 + sr;
      int grow = rowBase + row;
      int gr = (grow < M) ? grow : 0;
      u16x8 v = *reinterpret_cast<const u16x8*>(Asrc + gr * DD + kk + sc);
      int kb = (sc * 2) ^ ((row & 7) << 4);
      *reinterpret_cast<u16x8*>((char*)lA + row * 128 + kb) = v;
    }
#pragma unroll
    for (int it = 0; it < 4; ++it) {
      int row = it * 32 + sr;  // n within tile
      u16x8 v = *reinterpret_cast<const u16x8*>(WcT + (colBase + row) * KK + k0 + sc);
      int kb = (sc * 2) ^ ((row & 7) << 4);
      *reinterpret_cast<u16x8*>((char*)lB + row * 128 + kb) = v;
    }
    __syncthreads();

#pragma unroll
    for (int ks = 0; ks < 2; ++ks) {
      const int kbyte = ks * 64 + (lane >> 4) * 16;
      bf16x8 af[4], bfg[4];
#pragma unroll
      for (int m = 0; m < 4; ++m) {
        int row = wr * 64 + m * 16 + (lane & 15);
        af[m] = *reinterpret_cast<const bf16x8*>((const char*)lA + row * 128 + (kbyte ^ ((row & 7) << 4)));
      }
#pragma unroll
      for (int n = 0; n < 4; ++n) {
        int row = wc * 64 + n * 16 + (lane & 15);
        bfg[n] = *reinterpret_cast<const bf16x8*>((const char*)lB + row * 128 + (kbyte ^ ((row & 7) << 4)));
      }
#pragma unroll
      for (int m = 0; m < 4; ++m)
#pragma unroll
        for (int n = 0; n < 4; ++n)
          acc[m][n] = __builtin_amdgcn_mfma_f32_16x16x32_bf16(af[m], bfg[n], acc[m][n], 0, 0, 0);
    }
  }

  // epilogue: D layout col = lane&15, row = (lane>>4)*4 + reg  [m89-verified]
  const int lrow = (lane >> 4) * 4;
  const int lcol = lane & 15;
#pragma unroll
  for (int n = 0; n < 4; ++n) {
    const int gcol = colBase + wc * 64 + n * 16 + lcol;
    const float bv = bias[gcol];
#pragma unroll
    for (int m = 0; m < 4; ++m) {
#pragma unroll
      for (int r = 0; r < 4; ++r) {
        const int grow = rowBase + wr * 64 + m * 16 + lrow + r;
        if (grow < M) {
          float v = acc[m][n][r] + bv;
          if (LAYER == 1) {
            v = fmaxf(v, 0.0f);
            outb[grow * DD + gcol] = f2bf(v);
          } else {
            outf[grow * DD + gcol] = v;
          }
        }
      }
    }
  }
}

// ---------------- launch ----------------
extern "C" void kernel_launch(void* const* d_in, const int* in_sizes, int n_in,
                              void* d_out, int out_size, void* d_ws, size_t ws_size,
                              hipStream_t stream) {
  const float* x    = (const float*)d_in[0];
  const int*   ei   = (const int*)d_in[1];
  const float* W1l  = (const float*)d_in[2];
  const float* b1   = (const float*)d_in[3];
  const float* W1r  = (const float*)d_in[4];
  const float* W2l  = (const float*)d_in[5];
  const float* b2   = (const float*)d_in[6];
  const float* W2r  = (const float*)d_in[7];
  float* out = (float*)d_out;

  const int* srcIdx = ei;        // edge_index[0]
  const int* tgtIdx = ei + NE;   // edge_index[1]

  char* ws = (char*)d_ws;
  // workspace layout (bytes)
  int* cnt    = (int*)(ws + 0);                       // 50000*16*4 = 3,200,000
  int* col    = (int*)(ws + 3200000);                 // 50000*128*4 = 25,600,000
  u16* x_bf   = (u16*)(ws + 28800000);                // 25,600,000
  u16* h_bf   = (u16*)(ws + 54400000);                // 25,600,000
  u16* agg_bf = (u16*)(ws + 80000000);                // 25,600,000
  u16* Wc1T   = (u16*)(ws + 105600000);               // 262,144
  u16* Wc2T   = (u16*)(ws + 105862144);               // 262,144
  // total ~106.1 MB

  hipMemsetAsync(cnt, 0, NN * CSTR * sizeof(int), stream);
  k_fill2<<<(NE + 255) / 256, 256, 0, stream>>>(srcIdx, tgtIdx, cnt, col);

  k_f32_to_bf16<<<(NN * DD / 4 + 255) / 256, 256, 0, stream>>>(x, x_bf, NN * DD / 4);
  k_make_wcT<<<1024, 256, 0, stream>>>(W1l, W1r, W2l, W2r, Wc1T, Wc2T);

  dim3 ggrid((NN + BM - 1) / BM, DD / BN);

  // layer 1
  k_aggregate<<<NN / 4, 256, 0, stream>>>(x_bf, cnt, col, agg_bf);
  k_gemm_fused<1><<<ggrid, 256, 0, stream>>>(agg_bf, x_bf, Wc1T, b1, h_bf, nullptr, NN);
  // layer 2
  k_aggregate<<<NN / 4, 256, 0, stream>>>(h_bf, cnt, col, agg_bf);
  k_gemm_fused<2><<<ggrid, 256, 0, stream>>>(agg_bf, h_bf, Wc2T, b2, nullptr, out, NN);
}

// Round 7
// 236.394 us; speedup vs baseline: 1.9061x; 1.0277x over previous
//
#include <hip/hip_runtime.h>
#include <hip/hip_bf16.h>

#define NN 50000
#define NE 800000
#define DD 256
#define KK 512    // concat K for fused GEMM
#define PAD 128   // padded CSR row stride (max deg ~45 at 8 sigma; unreachable)
#define CSTR 16   // cnt stride in ints (64 B -> one cacheline per counter)

// prep-kernel block ranges
#define FB 3125    // fill blocks   (3125*256 = 800000 = NE)
#define CB 12500   // convert blocks(12500*256*4 = 12.8M elems = NN*DD)
#define WB 1024    // wcT blocks    (1024*256 = 262144 = 2*DD*KK/... both layers)

typedef unsigned short u16;
typedef unsigned int   u32;
typedef __attribute__((ext_vector_type(8))) __bf16 bf16x8;
typedef __attribute__((ext_vector_type(4))) float  f32x4;
typedef __attribute__((ext_vector_type(8))) u16    u16x8;
typedef __attribute__((ext_vector_type(4))) u16    u16x4;

static __device__ __forceinline__ u16 f2bf(float f) {
  u32 u = __float_as_uint(f);
  u32 r = (u + 0x7FFFu + ((u >> 16) & 1u)) >> 16;
  return (u16)r;
}
static __device__ __forceinline__ float bf2f(u16 h) {
  return __uint_as_float(((u32)h) << 16);
}

// ---------------- fused prep: CSR fill + f32->bf16 + WcT build ----------------
// Block-range fusion: fill blocks are latency-bound (atomics), convert blocks
// are BW-bound -> running them concurrently hides the conversion stream.
__global__ void k_prep(const int* __restrict__ src, const int* __restrict__ tgt,
                       int* __restrict__ cnt, int* __restrict__ col,
                       const float* __restrict__ x, u16* __restrict__ x_bf,
                       const float* __restrict__ W1l, const float* __restrict__ W1r,
                       const float* __restrict__ W2l, const float* __restrict__ W2r,
                       u16* __restrict__ Wc1T, u16* __restrict__ Wc2T) {
  const int b = blockIdx.x;
  if (b < FB) {
    // CSR fill (histogram-as-cursor, padded rows)
    int i = b * 256 + threadIdx.x;
    int t = tgt[i];
    int p = atomicAdd(&cnt[t * CSTR], 1);
    if (p < PAD) col[t * PAD + p] = src[i];
  } else if (b < FB + CB) {
    // x -> bf16, 4 floats/thread
    int i = (b - FB) * 256 + threadIdx.x;
    const float4 v = *reinterpret_cast<const float4*>(x + i * 4);
    u16x4 o; o.x = f2bf(v.x); o.y = f2bf(v.y); o.z = f2bf(v.z); o.w = f2bf(v.w);
    *reinterpret_cast<u16x4*>(x_bf + i * 4) = o;
  } else {
    // WcT[n][k] (bf16 [256][512]) for both layers
    int gid = (b - FB - CB) * 256 + threadIdx.x;  // 262144 total
    int layer = gid >> 17;
    int idx = gid & 131071;
    int n = idx >> 9, k = idx & 511;
    const float* Wl = layer ? W2l : W1l;
    const float* Wr = layer ? W2r : W1r;
    u16* WcT = layer ? Wc2T : Wc1T;
    float v = (k < DD) ? Wl[k * DD + n] : Wr[(k - DD) * DD + n];
    WcT[idx] = f2bf(v);
  }
}

// ---------------- mean aggregation (padded CSR) ----------------
// one wave per node; half-wave (32 lanes) per edge, 16 B (8 feats)/lane.
// 4 edges in flight per half-wave per iteration (MLP=4).
__global__ void k_aggregate(const u16* __restrict__ feat, const int* __restrict__ cnt,
                            const int* __restrict__ col, u16* __restrict__ out) {
  const int wave = threadIdx.x >> 6;
  const int lane = threadIdx.x & 63;
  const int half = lane >> 5;
  const int l32 = lane & 31;
  const int node = blockIdx.x * 4 + wave;
  int deg = cnt[node * CSTR];
  if (deg > PAD) deg = PAD;       // unreachable clamp, keeps mean consistent
  const int s = node * PAD, e = s + deg;
  const int fo = l32 * 8;  // 8 bf16 = 16 B per lane
  float a[8] = {0.f, 0.f, 0.f, 0.f, 0.f, 0.f, 0.f, 0.f};

  int i = s + half;
  for (; i + 6 < e; i += 8) {
    int c0 = col[i], c1 = col[i + 2], c2 = col[i + 4], c3 = col[i + 6];
    u16x8 v0 = *reinterpret_cast<const u16x8*>(feat + c0 * DD + fo);
    u16x8 v1 = *reinterpret_cast<const u16x8*>(feat + c1 * DD + fo);
    u16x8 v2 = *reinterpret_cast<const u16x8*>(feat + c2 * DD + fo);
    u16x8 v3 = *reinterpret_cast<const u16x8*>(feat + c3 * DD + fo);
#pragma unroll
    for (int j = 0; j < 8; ++j) a[j] += bf2f(v0[j]);
#pragma unroll
    for (int j = 0; j < 8; ++j) a[j] += bf2f(v1[j]);
#pragma unroll
    for (int j = 0; j < 8; ++j) a[j] += bf2f(v2[j]);
#pragma unroll
    for (int j = 0; j < 8; ++j) a[j] += bf2f(v3[j]);
  }
  for (; i < e; i += 2) {
    int c = col[i];
    u16x8 v = *reinterpret_cast<const u16x8*>(feat + c * DD + fo);
#pragma unroll
    for (int j = 0; j < 8; ++j) a[j] += bf2f(v[j]);
  }
#pragma unroll
  for (int j = 0; j < 8; ++j) a[j] += __shfl_xor(a[j], 32, 64);

  if (half == 0) {
    const float scale = (deg > 0) ? 1.0f / (float)deg : 0.0f;
    u16x8 o;
#pragma unroll
    for (int j = 0; j < 8; ++j) o[j] = f2bf(a[j] * scale);
    *reinterpret_cast<u16x8*>(out + node * DD + fo) = o;
  }
}

// ---------------- fused GEMM: out = [A0|A1] @ Wc + bias (+relu) ----------------
// BM=64 x BN=256 (full width -> A streamed exactly once). 4 waves, 64x64 each.
#define BM 64
#define BN 256
#define BK 64

template <int LAYER>
__global__ void k_gemm_fused(const u16* __restrict__ A0, const u16* __restrict__ A1,
                             const u16* __restrict__ WcT, const float* __restrict__ bias,
                             u16* __restrict__ outb, float* __restrict__ outf, int M) {
  __shared__ alignas(16) u16 lA[BM * BK];   // 8 KB
  __shared__ alignas(16) u16 lB[BN * BK];   // 32 KB
  const int tid = threadIdx.x;
  const int rowBase = blockIdx.x * BM;
  const int wave = tid >> 6, lane = tid & 63;
  const int wc = wave;  // 4 waves across N, each 64 cols

  f32x4 acc[4][4] = {};

  const int sr = tid >> 3;          // 0..31 staging row within 32-row group
  const int sc = (tid & 7) * 8;     // bf16 col offset 0..56

  for (int k0 = 0; k0 < KK; k0 += BK) {
    if (k0) __syncthreads();
    const u16* Asrc = (k0 < DD) ? A0 : A1;
    const int kk = k0 & (DD - 1);
    // stage A: 64 x 64 bf16 (XOR-swizzled rows)
#pragma unroll
    for (int it = 0; it < 2; ++it) {
      int row = it * 32 + sr;
      int grow = rowBase + row;
      int gr = (grow < M) ? grow : 0;
      u16x8 v = *reinterpret_cast<const u16x8*>(Asrc + gr * DD + kk + sc);
      int kb = (sc * 2) ^ ((row & 7) << 4);
      *reinterpret_cast<u16x8*>((char*)lA + row * 128 + kb) = v;
    }
    // stage B (WcT[n][k]): 256 x 64 bf16
#pragma unroll
    for (int it = 0; it < 8; ++it) {
      int row = it * 32 + sr;  // n 0..255
      u16x8 v = *reinterpret_cast<const u16x8*>(WcT + row * KK + k0 + sc);
      int kb = (sc * 2) ^ ((row & 7) << 4);
      *reinterpret_cast<u16x8*>((char*)lB + row * 128 + kb) = v;
    }
    __syncthreads();

#pragma unroll
    for (int ks = 0; ks < 2; ++ks) {
      const int kbyte = ks * 64 + (lane >> 4) * 16;
      bf16x8 af[4], bfg[4];
#pragma unroll
      for (int m = 0; m < 4; ++m) {
        int row = m * 16 + (lane & 15);
        af[m] = *reinterpret_cast<const bf16x8*>((const char*)lA + row * 128 + (kbyte ^ ((row & 7) << 4)));
      }
#pragma unroll
      for (int n = 0; n < 4; ++n) {
        int row = wc * 64 + n * 16 + (lane & 15);
        bfg[n] = *reinterpret_cast<const bf16x8*>((const char*)lB + row * 128 + (kbyte ^ ((row & 7) << 4)));
      }
#pragma unroll
      for (int m = 0; m < 4; ++m)
#pragma unroll
        for (int n = 0; n < 4; ++n)
          acc[m][n] = __builtin_amdgcn_mfma_f32_16x16x32_bf16(af[m], bfg[n], acc[m][n], 0, 0, 0);
    }
  }

  // epilogue: D layout col = lane&15, row = (lane>>4)*4 + reg  [m89-verified]
  const int lrow = (lane >> 4) * 4;
  const int lcol = lane & 15;
#pragma unroll
  for (int n = 0; n < 4; ++n) {
    const int gcol = wc * 64 + n * 16 + lcol;
    const float bv = bias[gcol];
#pragma unroll
    for (int m = 0; m < 4; ++m) {
#pragma unroll
      for (int r = 0; r < 4; ++r) {
        const int grow = rowBase + m * 16 + lrow + r;
        if (grow < M) {
          float v = acc[m][n][r] + bv;
          if (LAYER == 1) {
            v = fmaxf(v, 0.0f);
            outb[grow * DD + gcol] = f2bf(v);
          } else {
            outf[grow * DD + gcol] = v;
          }
        }
      }
    }
  }
}

// ---------------- launch ----------------
extern "C" void kernel_launch(void* const* d_in, const int* in_sizes, int n_in,
                              void* d_out, int out_size, void* d_ws, size_t ws_size,
                              hipStream_t stream) {
  const float* x    = (const float*)d_in[0];
  const int*   ei   = (const int*)d_in[1];
  const float* W1l  = (const float*)d_in[2];
  const float* b1   = (const float*)d_in[3];
  const float* W1r  = (const float*)d_in[4];
  const float* W2l  = (const float*)d_in[5];
  const float* b2   = (const float*)d_in[6];
  const float* W2r  = (const float*)d_in[7];
  float* out = (float*)d_out;

  const int* srcIdx = ei;        // edge_index[0]
  const int* tgtIdx = ei + NE;   // edge_index[1]

  char* ws = (char*)d_ws;
  int* cnt    = (int*)(ws + 0);                       // 3,200,000
  int* col    = (int*)(ws + 3200000);                 // 25,600,000
  u16* x_bf   = (u16*)(ws + 28800000);                // 25,600,000
  u16* h_bf   = (u16*)(ws + 54400000);                // 25,600,000
  u16* agg_bf = (u16*)(ws + 80000000);                // 25,600,000
  u16* Wc1T   = (u16*)(ws + 105600000);               // 262,144
  u16* Wc2T   = (u16*)(ws + 105862144);               // 262,144

  hipMemsetAsync(cnt, 0, NN * CSTR * sizeof(int), stream);
  k_prep<<<FB + CB + WB, 256, 0, stream>>>(srcIdx, tgtIdx, cnt, col, x, x_bf,
                                           W1l, W1r, W2l, W2r, Wc1T, Wc2T);

  const int ggrid = (NN + BM - 1) / BM;  // 782

  // layer 1
  k_aggregate<<<NN / 4, 256, 0, stream>>>(x_bf, cnt, col, agg_bf);
  k_gemm_fused<1><<<ggrid, 256, 0, stream>>>(agg_bf, x_bf, Wc1T, b1, h_bf, nullptr, NN);
  // layer 2
  k_aggregate<<<NN / 4, 256, 0, stream>>>(h_bf, cnt, col, agg_bf);
  k_gemm_fused<2><<<ggrid, 256, 0, stream>>>(agg_bf, h_bf, Wc2T, b2, nullptr, out, NN);
}